// Round 1
// baseline (36.345 us; speedup 1.0000x reference)
//
#include <hip/hip_runtime.h>

// Problem geometry (fixed by the reference):
//   val  : (B=16, H=64, W=64, C=128) float32
//   mask : same shape, int32 flat index into (B, H*2, W*2, C) incl. batch offset
//   out  : (B, 128, 128, 128) float32 — val scattered at mask, zeros elsewhere.
//
// Gather formulation: each output element reads the one mask element that
// could point at it and selects val or 0. Fully coalesced, single pass,
// no memset needed (every output element is written each call).

constexpr int B  = 16;
constexpr int H  = 64;
constexpr int W  = 64;
constexpr int C  = 128;
constexpr int H2 = 128;
constexpr int W2 = 128;
constexpr int NOUT = B * H2 * W2 * C;   // 33,554,432

__global__ __launch_bounds__(256)
void unpool_gather_kernel(const float* __restrict__ val,
                          const int*   __restrict__ mask,
                          float*       __restrict__ out)
{
    int t   = blockIdx.x * blockDim.x + threadIdx.x;
    int idx = t << 2;                 // flat output index of first of 4 elems
    if (idx >= NOUT) return;

    // Decompose idx = ((b*H2 + y)*W2 + x)*C + c   (C=128, W2=128, H2=128)
    int c    = idx & (C - 1);
    int rest = idx >> 7;              // / C
    int x    = rest & (W2 - 1);
    rest   >>= 7;                     // / W2
    int y    = rest & (H2 - 1);
    int b    = rest >> 7;             // / H2

    int h = y >> 1;
    int w = x >> 1;
    int moff = ((b * H + h) * W + w) * C + c;   // source (pooled) flat index

    const int4   m = *reinterpret_cast<const int4*>(mask + moff);
    const float4 v = *reinterpret_cast<const float4*>(val  + moff);

    float4 o;
    o.x = (m.x == idx + 0) ? v.x : 0.0f;
    o.y = (m.y == idx + 1) ? v.y : 0.0f;
    o.z = (m.z == idx + 2) ? v.z : 0.0f;
    o.w = (m.w == idx + 3) ? v.w : 0.0f;

    *reinterpret_cast<float4*>(out + idx) = o;
}

extern "C" void kernel_launch(void* const* d_in, const int* in_sizes, int n_in,
                              void* d_out, int out_size, void* d_ws, size_t ws_size,
                              hipStream_t stream)
{
    const float* val  = (const float*)d_in[0];
    const int*   mask = (const int*)d_in[1];
    float*       out  = (float*)d_out;

    const int n_threads = NOUT / 4;           // 8,388,608
    const int block = 256;
    const int grid  = n_threads / block;      // 32,768
    unpool_gather_kernel<<<grid, block, 0, stream>>>(val, mask, out);
}

// Round 3
// 33.620 us; speedup vs baseline: 1.0811x; 1.0811x over previous
//
#include <hip/hip_runtime.h>

// Max-unpool, window formulation:
//   val  : (B=16, H=64, W=64, C=128) float32
//   mask : same shape, int32 flat index into (B,128,128,128) incl. batch offset
//   out  : (B, 128, 128, 128) float32
//
// Each thread owns 4 consecutive channels of one pooled (b,h,w): reads the
// int4 mask + float4 val ONCE, decodes the in-window target (dh,dw) from the
// mask bits, and writes the four covering output float4s (2x2 window).
// Every output element is written each call (no memset needed).
// Non-temporal stores keep the write stream from evicting inputs in L2/L3.

typedef float f32x4 __attribute__((ext_vector_type(4)));
typedef int   i32x4 __attribute__((ext_vector_type(4)));

constexpr int B  = 16;
constexpr int H  = 64;
constexpr int W  = 64;
constexpr int C  = 128;
constexpr int H2 = 128;
constexpr int W2 = 128;
constexpr int NPOOL = B * H * W * C;        // 8,388,608 input elements

__global__ __launch_bounds__(256)
void unpool_window_kernel(const float* __restrict__ val,
                          const int*   __restrict__ mask,
                          float*       __restrict__ out)
{
    int t    = blockIdx.x * blockDim.x + threadIdx.x;
    int moff = t << 2;                       // flat pooled index of first of 4 chans

    // moff = ((b*H + h)*W + w)*C + c ; C=128, W=64, H=64
    int w = (moff >> 7)  & (W - 1);
    int h = (moff >> 13) & (H - 1);
    int b =  moff >> 19;
    int c =  moff & (C - 1);

    const i32x4 m = *reinterpret_cast<const i32x4*>(mask + moff);
    const f32x4 v = *reinterpret_cast<const f32x4*>(val  + moff);

    // mask = b*(H2*W2*C) + (2h+dh)*(W2*C) + (2w+dw)*C + c
    //   W2*C = 16384 = 2^14 ; C = 128 = 2^7
    //   dw = bit7 -> (m>>7)&1 ; dh = bit14 -> (m>>14)&1 ; sel = dh*2+dw
    int s0 = ((m.x >> 13) & 2) | ((m.x >> 7) & 1);
    int s1 = ((m.y >> 13) & 2) | ((m.y >> 7) & 1);
    int s2 = ((m.z >> 13) & 2) | ((m.z >> 7) & 1);
    int s3 = ((m.w >> 13) & 2) | ((m.w >> 7) & 1);

    f32x4 q00, q01, q10, q11;
    q00.x = (s0 == 0) ? v.x : 0.0f;  q01.x = (s0 == 1) ? v.x : 0.0f;
    q10.x = (s0 == 2) ? v.x : 0.0f;  q11.x = (s0 == 3) ? v.x : 0.0f;
    q00.y = (s1 == 0) ? v.y : 0.0f;  q01.y = (s1 == 1) ? v.y : 0.0f;
    q10.y = (s1 == 2) ? v.y : 0.0f;  q11.y = (s1 == 3) ? v.y : 0.0f;
    q00.z = (s2 == 0) ? v.z : 0.0f;  q01.z = (s2 == 1) ? v.z : 0.0f;
    q10.z = (s2 == 2) ? v.z : 0.0f;  q11.z = (s2 == 3) ? v.z : 0.0f;
    q00.w = (s3 == 0) ? v.w : 0.0f;  q01.w = (s3 == 1) ? v.w : 0.0f;
    q10.w = (s3 == 2) ? v.w : 0.0f;  q11.w = (s3 == 3) ? v.w : 0.0f;

    // out base: ((b*H2 + 2h)*W2 + 2w)*C + c
    int base = (((b * H2 + 2 * h) * W2) + 2 * w) * C + c;
    float* p00 = out + base;                 // (2h  , 2w  )
    float* p10 = p00 + W2 * C;               // (2h+1, 2w  )

    __builtin_nontemporal_store(q00, reinterpret_cast<f32x4*>(p00));
    __builtin_nontemporal_store(q01, reinterpret_cast<f32x4*>(p00 + C));
    __builtin_nontemporal_store(q10, reinterpret_cast<f32x4*>(p10));
    __builtin_nontemporal_store(q11, reinterpret_cast<f32x4*>(p10 + C));
}

extern "C" void kernel_launch(void* const* d_in, const int* in_sizes, int n_in,
                              void* d_out, int out_size, void* d_ws, size_t ws_size,
                              hipStream_t stream)
{
    const float* val  = (const float*)d_in[0];
    const int*   mask = (const int*)d_in[1];
    float*       out  = (float*)d_out;

    const int n_threads = NPOOL / 4;         // 2,097,152
    const int block = 256;
    const int grid  = n_threads / block;     // 8,192
    unpool_window_kernel<<<grid, block, 0, stream>>>(val, mask, out);
}